// Round 1
// baseline (779.290 us; speedup 1.0000x reference)
//
#include <hip/hip_runtime.h>

typedef __bf16 bf16;
typedef __attribute__((ext_vector_type(8))) __bf16 bf16x8;
typedef __attribute__((ext_vector_type(4))) float f32x4;

#define MFMA16(a, b, c) __builtin_amdgcn_mfma_f32_16x16x32_bf16(a, b, c, 0, 0, 0)

constexpr int Tn = 128, Cn = 128, Hn = 4, Dn = 32;
constexpr float SCALE = 0.08838834764831845f;  // C^-0.5 = 1/sqrt(128)

constexpr int XS_STR = 136;              // x / V^T row stride (pad keeps banks even, 16B-aligned)
constexpr int QK_STR = 40;               // Q/K/P-chunk row stride
constexpr int Q_OFF  = 0;                // Q: 128 x 40      (also P-chunk / O staging)
constexpr int K_OFF  = 128 * QK_STR;     // K: 128 x 40
constexpr int VT_OFF = 2 * 128 * QK_STR; // V^T: 32 x 136
constexpr int U_SIZE = VT_OFF + 32 * XS_STR;   // 14592 el -> total LDS 64000 B (2 blocks/CU)

// ---- repack weights into MFMA B-fragment order (bf16), once per launch ----
// frag layout: lane l holds B[k=(l>>4)*8+j][n=nt*16+(l&15)], 8 bf16 = 16 B.
// QKV frags: id = (h*6 + nt)*4 + ks   (nt over 96 cols: 0-1 Q, 2-3 K, 4-5 V; ks over C)
// Wp  frags: id = 96 + nt*4 + ks      (nt over cout; ks over c; ks==h slice used per head)
__global__ void prepack_weights(const float* __restrict__ Wq, const float* __restrict__ Wk,
                                const float* __restrict__ Wv, const float* __restrict__ Wp,
                                uint4* __restrict__ frags) {
  int tid = blockIdx.x * blockDim.x + threadIdx.x;   // 8192 threads
  int frag = tid >> 6, lane = tid & 63;
  int q = lane >> 4, c16 = lane & 15;
  union { bf16 e[8]; uint4 v; } o;
  if (frag < 96) {
    int h = frag / 24, rem = frag % 24;
    int nt = rem >> 2, ks = rem & 3;
    int oc = nt * 16 + c16;            // 0..95 within head
    int mat = oc >> 5, d = oc & 31;
    const float* W = (mat == 0) ? Wq : ((mat == 1) ? Wk : Wv);
    const float* src = W + h * (Cn * Dn) + (ks * 32 + q * 8) * Dn + d;
#pragma unroll
    for (int j = 0; j < 8; ++j) o.e[j] = (bf16)src[j * Dn];
  } else {
    int f = frag - 96;
    int nt = f >> 2, ks = f & 3;
    int cout = nt * 16 + c16;
    const float* src = Wp + cout * Cn + ks * 32 + q * 8;  // Wp^T[c][cout] = Wp[cout][c]
#pragma unroll
    for (int j = 0; j < 8; ++j) o.e[j] = (bf16)src[j];
  }
  frags[frag * 64 + lane] = o.v;
}

// ---- fused MHA: one block per batch element, 512 threads = 8 waves ----
__global__ __launch_bounds__(512, 2) void mha_fused(
    const float* __restrict__ x, const bf16* __restrict__ wqkv,
    const bf16* __restrict__ wpf, const float* __restrict__ bp,
    float* __restrict__ out) {
  __shared__ __align__(16) bf16 xs[Tn * XS_STR];
  __shared__ __align__(16) bf16 U[U_SIZE];

  const int b = blockIdx.x;
  const int tid = threadIdx.x;
  const int w = tid >> 6;        // wave id = attention m-tile
  const int lane = tid & 63;
  const int quad = lane >> 4;
  const int c16 = lane & 15;

  // stage x (fp32 -> bf16) into LDS, coalesced float4
  const float* xb = x + (size_t)b * (Tn * Cn);
  {
    const float4* xv = (const float4*)xb;
#pragma unroll
    for (int i = 0; i < 8; ++i) {
      int idx = tid + i * 512;        // 0..4095 float4s
      int t = idx >> 5;
      int c = (idx & 31) * 4;
      float4 v = xv[idx];
      bf16* dst = &xs[t * XS_STR + c];
      dst[0] = (bf16)v.x; dst[1] = (bf16)v.y;
      dst[2] = (bf16)v.z; dst[3] = (bf16)v.w;
    }
  }

  f32x4 yacc[8];
#pragma unroll
  for (int i = 0; i < 8; ++i) yacc[i] = (f32x4){0.f, 0.f, 0.f, 0.f};

  __syncthreads();

  const int mq = w & 3;   // projection: m-quarter (2 mtiles)
  const int ng = w >> 2;  // projection: ntile triple

  for (int h = 0; h < Hn; ++h) {
    // ---- QKV_h = xs @ [Wq_h | Wk_h | Wv_h]  (24 wave-tasks, balanced) ----
    bf16x8 afr[2][4];
#pragma unroll
    for (int mt = 0; mt < 2; ++mt)
#pragma unroll
      for (int ks = 0; ks < 4; ++ks)
        afr[mt][ks] = *(const bf16x8*)&xs[((mq * 2 + mt) * 16 + c16) * XS_STR + ks * 32 + quad * 8];

#pragma unroll
    for (int i = 0; i < 3; ++i) {
      const int nt = ng * 3 + i;   // 0..5
      f32x4 acc0 = {0.f, 0.f, 0.f, 0.f}, acc1 = {0.f, 0.f, 0.f, 0.f};
#pragma unroll
      for (int ks = 0; ks < 4; ++ks) {
        bf16x8 bfr = ((const bf16x8*)wqkv)[((h * 6 + nt) * 4 + ks) * 64 + lane];
        acc0 = MFMA16(afr[0][ks], bfr, acc0);
        acc1 = MFMA16(afr[1][ks], bfr, acc1);
      }
      const int oc = nt * 16 + c16;
      const int mat = oc >> 5;     // 0=Q 1=K 2=V
      const int d = oc & 31;
#pragma unroll
      for (int mt = 0; mt < 2; ++mt) {
        const int tb = (mq * 2 + mt) * 16 + quad * 4;
        const f32x4 a = mt ? acc1 : acc0;
#pragma unroll
        for (int r = 0; r < 4; ++r) {
          bf16 v = (bf16)a[r];
          if (mat == 0)      U[Q_OFF + (tb + r) * QK_STR + d] = v;
          else if (mat == 1) U[K_OFF + (tb + r) * QK_STR + d] = v;
          else               U[VT_OFF + d * XS_STR + (tb + r)] = v;  // V stored transposed
        }
      }
    }
    __syncthreads();

    // ---- attention: wave w owns rows [w*16, w*16+16) ----
    bf16x8 qf = *(const bf16x8*)&U[Q_OFF + (w * 16 + c16) * QK_STR + quad * 8];
    bf16x8 vf[4][2];
#pragma unroll
    for (int ks = 0; ks < 4; ++ks) {
      if (ks <= (w >> 1)) {   // wave-uniform causal skip
#pragma unroll
        for (int n = 0; n < 2; ++n)
          vf[ks][n] = *(const bf16x8*)&U[VT_OFF + (n * 16 + c16) * XS_STR + ks * 32 + quad * 8];
      }
    }
    f32x4 s[8];
#pragma unroll
    for (int nt = 0; nt < 8; ++nt) {
      if (nt <= w) {
        bf16x8 kf = *(const bf16x8*)&U[K_OFF + (nt * 16 + c16) * QK_STR + quad * 8];
        f32x4 z = {0.f, 0.f, 0.f, 0.f};
        s[nt] = MFMA16(qf, kf, z);
      }
    }

    // ---- causal softmax, fully in registers (rows live in one 16-lane quad group) ----
#pragma unroll
    for (int r = 0; r < 4; ++r) {
      const int t = w * 16 + quad * 4 + r;
      float m = -1e30f;
#pragma unroll
      for (int nt = 0; nt < 8; ++nt) {
        if (nt <= w) {
          float v = s[nt][r] * SCALE;
          if (nt * 16 + c16 > t) v = -1e30f;   // causal mask (per-lane select)
          s[nt][r] = v;
          m = fmaxf(m, v);
        }
      }
      m = fmaxf(m, __shfl_xor(m, 1));
      m = fmaxf(m, __shfl_xor(m, 2));
      m = fmaxf(m, __shfl_xor(m, 4));
      m = fmaxf(m, __shfl_xor(m, 8));
      float sum = 0.f;
#pragma unroll
      for (int nt = 0; nt < 8; ++nt) {
        if (nt <= w) {
          float e = __expf(s[nt][r] - m);
          s[nt][r] = e;
          sum += e;
        }
      }
      sum += __shfl_xor(sum, 1);
      sum += __shfl_xor(sum, 2);
      sum += __shfl_xor(sum, 4);
      sum += __shfl_xor(sum, 8);
      const float inv = 1.f / sum;
#pragma unroll
      for (int nt = 0; nt < 8; ++nt)
        if (nt <= w) s[nt][r] *= inv;
    }
    __syncthreads();   // all waves finished reading Q/K/V before P overwrites Q region

    // ---- O = P @ V_h, P chunked through Q region (wave-private rows, no barrier) ----
    f32x4 o0 = {0.f, 0.f, 0.f, 0.f}, o1 = {0.f, 0.f, 0.f, 0.f};
#pragma unroll
    for (int ks = 0; ks < 4; ++ks) {
      if (ks <= (w >> 1)) {
#pragma unroll
        for (int n = 0; n < 2; ++n) {
          const int nt = ks * 2 + n;
#pragma unroll
          for (int r = 0; r < 4; ++r) {
            float v = (nt <= w) ? s[nt][r] : 0.f;
            U[Q_OFF + (w * 16 + quad * 4 + r) * QK_STR + n * 16 + c16] = (bf16)v;
          }
        }
        bf16x8 pf = *(const bf16x8*)&U[Q_OFF + (w * 16 + c16) * QK_STR + quad * 8];
        o0 = MFMA16(pf, vf[ks][0], o0);
        o1 = MFMA16(pf, vf[ks][1], o1);
      }
    }

    // ---- Y += O_h @ Wp_h^T  (O_h round-trips own rows for A-layout) ----
#pragma unroll
    for (int n = 0; n < 2; ++n) {
      const f32x4 o = n ? o1 : o0;
#pragma unroll
      for (int r = 0; r < 4; ++r)
        U[Q_OFF + (w * 16 + quad * 4 + r) * QK_STR + n * 16 + c16] = (bf16)o[r];
    }
    bf16x8 of = *(const bf16x8*)&U[Q_OFF + (w * 16 + c16) * QK_STR + quad * 8];
#pragma unroll
    for (int nt = 0; nt < 8; ++nt) {
      bf16x8 wf = ((const bf16x8*)wpf)[(nt * 4 + h) * 64 + lane];
      yacc[nt] = MFMA16(of, wf, yacc[nt]);
    }
    __syncthreads();   // U free for next head's projection
  }

  // ---- epilogue: bias + fp32 store ----
  float* ob = out + (size_t)b * (Tn * Cn);
#pragma unroll
  for (int nt = 0; nt < 8; ++nt) {
    const float bias = bp[nt * 16 + c16];
#pragma unroll
    for (int r = 0; r < 4; ++r) {
      const int t = w * 16 + quad * 4 + r;
      ob[t * Cn + nt * 16 + c16] = yacc[nt][r] + bias;
    }
  }
}

extern "C" void kernel_launch(void* const* d_in, const int* in_sizes, int n_in,
                              void* d_out, int out_size, void* d_ws, size_t ws_size,
                              hipStream_t stream) {
  (void)in_sizes; (void)n_in; (void)out_size; (void)ws_size;
  const float* x  = (const float*)d_in[0];
  const float* Wq = (const float*)d_in[1];
  const float* Wk = (const float*)d_in[2];
  const float* Wv = (const float*)d_in[3];
  const float* Wp = (const float*)d_in[4];
  const float* bp = (const float*)d_in[5];
  bf16* frags = (bf16*)d_ws;   // 128 frags * 512 bf16 = 128 KiB of workspace
  prepack_weights<<<dim3(32), dim3(256), 0, stream>>>(Wq, Wk, Wv, Wp, (uint4*)frags);
  mha_fused<<<dim3(4096), dim3(512), 0, stream>>>(x, frags, frags + 96 * 512, bp,
                                                  (float*)d_out);
}

// Round 2
// 711.018 us; speedup vs baseline: 1.0960x; 1.0960x over previous
//
#include <hip/hip_runtime.h>

typedef __bf16 bf16;
typedef __attribute__((ext_vector_type(8))) __bf16 bf16x8;
typedef __attribute__((ext_vector_type(4))) float f32x4;

#define MFMA16(a, b, c) __builtin_amdgcn_mfma_f32_16x16x32_bf16(a, b, c, 0, 0, 0)

constexpr int QKS = 136;                    // LDS row stride (bf16): 272 B = odd*16 -> staggered banks
constexpr float SCALE = 0.08838834764831845f;  // C^-0.5

// ---------------- weight prepack ----------------
// 128 frags x 1 KiB in d_ws:
//  f in [0,64):  A-frags of [Q h0|Q h1|K h0|K h1]^T per iter (Wq pre-scaled by SCALE)
//                id = iter*32 + mt*4 + ks   (mt over 8 oc-tiles, ks over C)
//  f in [64,96): B-frags of Wv (cols d2 = 2 heads x 32), id = 64 + iter*16 + nt*4 + ks
//  f in [96,128): B-frags of Wp^T, id = 96 + nt*4 + h    (k-tile ks == head slice)
__global__ void prepack(const float* __restrict__ Wq, const float* __restrict__ Wk,
                        const float* __restrict__ Wv, const float* __restrict__ Wp,
                        uint4* __restrict__ frags) {
  int tid = blockIdx.x * blockDim.x + threadIdx.x;   // 8192 threads
  int f = tid >> 6, lane = tid & 63, quad = lane >> 4, c16 = lane & 15;
  union { bf16 e[8]; uint4 v; } o;
  if (f < 64) {
    int iter = f >> 5, rem = f & 31, mt = rem >> 2, ks = rem & 3;
    int oc = mt * 16 + c16;                       // row of [QK]^T
    int isK = oc >> 6, h = iter * 2 + ((oc >> 5) & 1), d = oc & 31;
    const float* W = isK ? Wk : Wq;
    const float* src = W + h * 4096 + (ks * 32 + quad * 8) * 32 + d;
    float sc = isK ? 1.f : SCALE;
#pragma unroll
    for (int j = 0; j < 8; ++j) o.e[j] = (bf16)(src[j * 32] * sc);
  } else if (f < 96) {
    int g = f - 64, iter = g >> 4, rem = g & 15, nt = rem >> 2, ks = rem & 3;
    int n = nt * 16 + c16, h = iter * 2 + (n >> 5), d = n & 31;
    const float* src = Wv + h * 4096 + (ks * 32 + quad * 8) * 32 + d;
#pragma unroll
    for (int j = 0; j < 8; ++j) o.e[j] = (bf16)src[j * 32];
  } else {
    int g = f - 96, nt = g >> 2, h = g & 3;
    const float* src = Wp + (nt * 16 + c16) * 128 + h * 32 + quad * 8;
#pragma unroll
    for (int j = 0; j < 8; ++j) o.e[j] = (bf16)src[j];
  }
  frags[f * 64 + lane] = o.v;
}

// ---------------- fused MHA: 1 block = 1 batch, 8 waves, 2 heads/iter ----------------
__global__ __launch_bounds__(512, 4) void mha2(
    const float* __restrict__ x, const bf16* __restrict__ fr,
    const float* __restrict__ bp, float* __restrict__ out) {
  __shared__ __align__(16) bf16 QK[128 * QKS];   // [t][col]: 0-63 Q(2 heads) / P / O, 64-127 K(2 heads)
  __shared__ __align__(16) bf16 VT[64 * QKS];    // [d2][t] (V transposed, 2 heads)

  const int b = blockIdx.x, tid = threadIdx.x;
  const int w = tid >> 6, lane = tid & 63, quad = lane >> 4, c16 = lane & 15;
  const bf16x8* frv = (const bf16x8*)fr;

  // x fragments for this wave's rows [16w,16w+16), loaded ONCE (A-frag of x == B-frag of x^T)
  const float* xr = x + (size_t)b * 16384 + (w * 16 + c16) * 128;
  bf16x8 xf[4];
#pragma unroll
  for (int ks = 0; ks < 4; ++ks) {
    const float4* s4 = (const float4*)(xr + ks * 32 + quad * 8);
    float4 a = s4[0], c = s4[1];
    union { bf16 e[8]; bf16x8 v; } u;
    u.e[0] = (bf16)a.x; u.e[1] = (bf16)a.y; u.e[2] = (bf16)a.z; u.e[3] = (bf16)a.w;
    u.e[4] = (bf16)c.x; u.e[5] = (bf16)c.y; u.e[6] = (bf16)c.z; u.e[7] = (bf16)c.w;
    xf[ks] = u.v;
  }

  f32x4 yacc[8];
#pragma unroll
  for (int i = 0; i < 8; ++i) yacc[i] = (f32x4){0.f, 0.f, 0.f, 0.f};

  for (int iter = 0; iter < 2; ++iter) {
    // ---- [Q|K]^T = W^T x^T : C-frag rows = oc -> b64 writes into row-major [t][oc] ----
#pragma unroll
    for (int mt = 0; mt < 8; ++mt) {
      f32x4 acc = {0.f, 0.f, 0.f, 0.f};
#pragma unroll
      for (int ks = 0; ks < 4; ++ks)
        acc = MFMA16(frv[(iter * 32 + mt * 4 + ks) * 64 + lane], xf[ks], acc);
      union { bf16 e[4]; uint2 u; } p;
#pragma unroll
      for (int r = 0; r < 4; ++r) p.e[r] = (bf16)acc[r];
      *(uint2*)&QK[(w * 16 + c16) * QKS + mt * 16 + quad * 4] = p.u;
    }
    // ---- V = x Wv : C-frag rows = t -> b64 writes into [d2][t] (V^T) ----
#pragma unroll
    for (int nt = 0; nt < 4; ++nt) {
      f32x4 acc = {0.f, 0.f, 0.f, 0.f};
#pragma unroll
      for (int ks = 0; ks < 4; ++ks)
        acc = MFMA16(xf[ks], frv[(64 + iter * 16 + nt * 4 + ks) * 64 + lane], acc);
      union { bf16 e[4]; uint2 u; } p;
#pragma unroll
      for (int r = 0; r < 4; ++r) p.e[r] = (bf16)acc[r];
      *(uint2*)&VT[(nt * 16 + c16) * QKS + w * 16 + quad * 4] = p.u;
    }
    __syncthreads();

    // ---- attention: wave w gets (h0, m=w) and (h1, m=7-w) -> 9 score tiles each, balanced ----
#pragma unroll
    for (int rep = 0; rep < 2; ++rep) {
      const int m = rep ? (7 - w) : w;
      const int hl = rep;
      const int qcol = hl * 32, kcol = 64 + hl * 32, vrow = hl * 32;

      // S^T = K Q^T : B-frag of Q^T reads Q row-major (b128)
      bf16x8 qf = *(const bf16x8*)&QK[(m * 16 + c16) * QKS + qcol + quad * 8];
      f32x4 st[8];
#pragma unroll
      for (int nt = 0; nt < 8; ++nt) {
        if (nt <= m) {
          bf16x8 kf = *(const bf16x8*)&QK[(nt * 16 + c16) * QKS + kcol + quad * 8];
          f32x4 z = {0.f, 0.f, 0.f, 0.f};
          st[nt] = MFMA16(kf, qf, z);   // lane: col t = m*16+c16, rows s = nt*16+quad*4+r
        }
      }
      // softmax over s (fixed t per lane): only diagonal tile needs the mask
      float mx = -1e30f;
#pragma unroll
      for (int nt = 0; nt < 8; ++nt) {
        if (nt < m) {
#pragma unroll
          for (int r = 0; r < 4; ++r) mx = fmaxf(mx, st[nt][r]);
        } else if (nt == m) {
#pragma unroll
          for (int r = 0; r < 4; ++r) {
            float v = (quad * 4 + r > c16) ? -1e30f : st[nt][r];
            st[nt][r] = v;
            mx = fmaxf(mx, v);
          }
        }
      }
      mx = fmaxf(mx, __shfl_xor(mx, 16));
      mx = fmaxf(mx, __shfl_xor(mx, 32));
      float sum = 0.f;
#pragma unroll
      for (int nt = 0; nt < 8; ++nt) {
        if (nt <= m) {
#pragma unroll
          for (int r = 0; r < 4; ++r) {
            float e = __expf(st[nt][r] - mx);
            st[nt][r] = e;
            sum += e;
          }
        }
      }
      sum += __shfl_xor(sum, 16);
      sum += __shfl_xor(sum, 32);
      const float inv = __builtin_amdgcn_rcpf(sum);   // folded into O below

      // O^T = V^T P^T, P chunked (32 s) through wave-private Q cols (b64 write, b128 read)
      f32x4 oa0 = {0.f, 0.f, 0.f, 0.f}, oa1 = {0.f, 0.f, 0.f, 0.f};
#pragma unroll
      for (int kc = 0; kc < 4; ++kc) {
        if (kc <= (m >> 1)) {
#pragma unroll
          for (int n2 = 0; n2 < 2; ++n2) {
            const int nt = kc * 2 + n2;
            union { bf16 e[4]; uint2 u; } p;
            if (nt <= m) {
#pragma unroll
              for (int r = 0; r < 4; ++r) p.e[r] = (bf16)st[nt][r];
            } else { p.u.x = 0u; p.u.y = 0u; }
            *(uint2*)&QK[(m * 16 + c16) * QKS + qcol + n2 * 16 + quad * 4] = p.u;
          }
          bf16x8 pf = *(const bf16x8*)&QK[(m * 16 + c16) * QKS + qcol + quad * 8];
          bf16x8 v0 = *(const bf16x8*)&VT[(vrow + c16) * QKS + kc * 32 + quad * 8];
          bf16x8 v1 = *(const bf16x8*)&VT[(vrow + 16 + c16) * QKS + kc * 32 + quad * 8];
          oa0 = MFMA16(v0, pf, oa0);
          oa1 = MFMA16(v1, pf, oa1);
        }
      }
      // stage O (normalized) into [t][d] at Q cols; O^T lane col t = c16 matches inv's lane map
      union { bf16 e[4]; uint2 u; } q0, q1;
#pragma unroll
      for (int r = 0; r < 4; ++r) {
        q0.e[r] = (bf16)(oa0[r] * inv);
        q1.e[r] = (bf16)(oa1[r] * inv);
      }
      *(uint2*)&QK[(m * 16 + c16) * QKS + hl * 32 + quad * 4] = q0.u;
      *(uint2*)&QK[(m * 16 + c16) * QKS + hl * 32 + 16 + quad * 4] = q1.u;
    }
    __syncthreads();

    // ---- Y += O_h Wp_h^T (k = 32 per head) ----
#pragma unroll
    for (int hl = 0; hl < 2; ++hl) {
      bf16x8 of = *(const bf16x8*)&QK[(w * 16 + c16) * QKS + hl * 32 + quad * 8];
      const int h = iter * 2 + hl;
#pragma unroll
      for (int nt = 0; nt < 8; ++nt)
        yacc[nt] = MFMA16(of, frv[(96 + nt * 4 + h) * 64 + lane], yacc[nt]);
    }
    __syncthreads();   // QK/VT free for next head pair
  }

  // ---- epilogue: bias + coalesced fp32 stores ----
  float* ob = out + (size_t)b * 16384;
#pragma unroll
  for (int nt = 0; nt < 8; ++nt) {
    const float bias = bp[nt * 16 + c16];
#pragma unroll
    for (int r = 0; r < 4; ++r)
      ob[(w * 16 + quad * 4 + r) * 128 + nt * 16 + c16] = yacc[nt][r] + bias;
  }
}

extern "C" void kernel_launch(void* const* d_in, const int* in_sizes, int n_in,
                              void* d_out, int out_size, void* d_ws, size_t ws_size,
                              hipStream_t stream) {
  (void)in_sizes; (void)n_in; (void)out_size; (void)ws_size;
  const float* x  = (const float*)d_in[0];
  const float* Wq = (const float*)d_in[1];
  const float* Wk = (const float*)d_in[2];
  const float* Wv = (const float*)d_in[3];
  const float* Wp = (const float*)d_in[4];
  const float* bp = (const float*)d_in[5];
  bf16* frags = (bf16*)d_ws;   // 128 frags * 1 KiB = 128 KiB
  prepack<<<dim3(32), dim3(256), 0, stream>>>(Wq, Wk, Wv, Wp, (uint4*)frags);
  mha2<<<dim3(4096), dim3(512), 0, stream>>>(x, frags, bp, (float*)d_out);
}